// Round 8
// baseline (331.219 us; speedup 1.0000x reference)
//
#include <hip/hip_runtime.h>

#define HW    256
#define HW2   65536      // HW*HW
#define BS    128
#define NT    1024       // scatter threads/block
#define QPB   16384      // float4 quads per image plane (HW2/4)

// ============================ 2-KERNEL PATH ================================
// ws layout: W16[BS][HW2] u16 (16 MB) | packed[BS][128*128] float4 (32 MB)
// Winner semantics: W[gy,gx] = max l (l=h*256+w) == reference scatter's
// last-in-row-major-order-wins; "no writer" (0) is output-equivalent to
// winner l=0 (both sample (0,0), valid). Proven absmax 0.0 rounds 1,3,4,6,7.

// Block = (batch, output-quarter). 512 blocks, 2/CU (64 KB LDS) -> full
// occupancy. Native ds_max_u32, each output cell owned by exactly one block
// (no partial-merge). The 4 sibling blocks (b, b+128, b+256, b+384) land on
// XCD b&7 under round-robin dispatch, so the 4x-duplicated grid/seg reads
// L2-hit. Epilogue: coalesced u16 winner write + even-row (depth*m,conf,m)
// pack for this quarter's input-row slice.
__global__ __launch_bounds__(NT, 8) void scatter_kernel(
        const float* __restrict__ grid,
        const float* __restrict__ seg,
        const float* __restrict__ conf,
        const float* __restrict__ depth,
        unsigned short* __restrict__ W16,
        float4* __restrict__ packed) {
    __shared__ unsigned int Wl[HW2 / 4];   // 64 KB: own-quarter winners (u32)
    __shared__ int red[16];
    __shared__ int flag_s;

    const int b    = blockIdx.x & (BS - 1);
    const int q    = blockIdx.x >> 7;      // output quarter 0..3
    const int tid  = threadIdx.x;
    const int wave = tid >> 6;
    const int lane = tid & 63;

    const float* segb   = seg   + (size_t)b * HW2;
    const float* confb  = conf  + (size_t)b * HW2;
    const float* depthb = depth + (size_t)b * HW2;

    // ---- Phase 0: zero W; read seg -> mbits; count for empty-mask flag ----
    {
        uint4* Wz = (uint4*)Wl;            // 4096 uint4
        #pragma unroll
        for (int k = 0; k < 4; ++k) Wz[tid + k * NT] = make_uint4(0u, 0u, 0u, 0u);
    }
    unsigned long long mbits = 0ULL;       // bit (k*4+j) = mask of pixel (tid+k*NT)*4+j
    int cnt = 0;
    {
        const float4* s4 = (const float4*)segb;
        #pragma unroll
        for (int k = 0; k < 16; ++k) {
            float4 v = s4[tid + k * NT];
            unsigned long long qm = (v.x > 0.5f ? 1ULL : 0ULL) | (v.y > 0.5f ? 2ULL : 0ULL) |
                                    (v.z > 0.5f ? 4ULL : 0ULL) | (v.w > 0.5f ? 8ULL : 0ULL);
            mbits |= qm << (k * 4);
            cnt += __popcll(qm);
        }
    }
    for (int off = 32; off > 0; off >>= 1) cnt += __shfl_down(cnt, off);
    if (lane == 0) red[wave] = cnt;
    __syncthreads();
    if (tid == 0) {
        int t = 0;
        #pragma unroll
        for (int w = 0; w < 16; ++w) t += red[w];
        flag_s = (t == 0) ? 1 : 0;
    }
    __syncthreads();
    const int flagb = flag_s;

    // ---- Phase 1: scatter own-quarter cells via native ds_max_u32 --------
    {
        const float4* gx4 = (const float4*)(grid + (size_t)(2 * b) * HW2);
        const float4* gy4 = (const float4*)(grid + (size_t)(2 * b + 1) * HW2);
        int masked_max = -1;  // masked pixels (gridm==0) all target cell (128,128)
        #pragma unroll 4
        for (int k = 0; k < 16; ++k) {
            int i = tid + k * NT;
            float4 X = gx4[i];
            float4 Y = gy4[i];
            int hw0 = i * 4;
            float xa[4] = {X.x, X.y, X.z, X.w};
            float ya[4] = {Y.x, Y.y, Y.z, Y.w};
            #pragma unroll
            for (int j = 0; j < 4; ++j) {
                bool m = flagb || ((mbits >> (k * 4 + j)) & 1ULL);
                if (m) {
                    float fx = (xa[j] + 1.0f) * 0.5f * 256.0f;  // trunc==floor (>=0)
                    float fy = (ya[j] + 1.0f) * 0.5f * 256.0f;
                    int gxi = min(max((int)fx, 0), HW - 1);
                    int gyi = min(max((int)fy, 0), HW - 1);
                    if ((gyi >> 6) == q)
                        atomicMax(&Wl[(gyi & 63) * HW + gxi], (unsigned int)(hw0 + j));
                } else {
                    masked_max = hw0 + j;  // k increases -> last seen is max
                }
            }
        }
        int mm = masked_max;
        for (int off = 32; off > 0; off >>= 1) mm = max(mm, __shfl_xor(mm, off));
        if (q == 2 && lane == 0 && mm >= 0)    // cell (128,128): 128>>6 == 2
            atomicMax(&Wl[(128 & 63) * HW + 128], (unsigned int)mm);
    }
    __syncthreads();

    // ---- Epilogue A: coalesced u16 winner write for own quarter ----------
    {
        unsigned int* Wout = (unsigned int*)(W16 + (size_t)b * HW2 + q * 16384);
        #pragma unroll
        for (int k = 0; k < 2; ++k) {
            int idx = tid + k * NT;            // uint4 index, 2048 total
            int base = idx * 8;
            uint4 w;
            w.x = Wl[base + 0] | (Wl[base + 1] << 16);
            w.y = Wl[base + 2] | (Wl[base + 3] << 16);
            w.z = Wl[base + 4] | (Wl[base + 5] << 16);
            w.w = Wl[base + 6] | (Wl[base + 7] << 16);
            ((uint4*)Wout)[idx] = w;
        }
    }

    // ---- Epilogue B: pack even rows of input-row slice [64q, 64q+64) -----
    // packed[b][iy/2][ix/2] = (depth*m, conf, m, 0) at even-even cells.
    {
        float4* packb = packed + (size_t)b * 16384;
        #pragma unroll
        for (int k = 0; k < 2; ++k) {
            int it = tid + k * NT;             // 0..2047
            int rl = it >> 6;                  // 0..31
            int qc = it & 63;                  // quad-col
            int r  = 64 * q + 2 * rl;          // even input row in slice
            int qr = r * 64 + qc;
            float4 d = ((const float4*)depthb)[qr];
            float4 c = ((const float4*)confb)[qr];
            float4 s = ((const float4*)segb)[qr];
            float m0 = (flagb || s.x > 0.5f) ? 1.0f : 0.0f;
            float m1 = (flagb || s.z > 0.5f) ? 1.0f : 0.0f;
            int p = (r >> 1) * 128 + 2 * qc;
            packb[p]     = make_float4(d.x * m0, c.x, m0, 0.0f);
            packb[p + 1] = make_float4(d.z * m1, c.z, m1, 0.0f);
        }
    }
}

// 2048 blocks x 256, 8/CU. Block->batch mapping keeps batch b on XCD b&7
// (same as scatter) so W16/packed reads L2-hit. One uint2 winner load + one
// random float4 into a 256KB/batch L2-resident footprint; ix/280 via LDS LUT.
__global__ __launch_bounds__(256, 8) void gather_kernel(
        const unsigned short* __restrict__ W16,
        const float4* __restrict__ packed,
        float* __restrict__ out) {
    __shared__ float lut[128];
    if (threadIdx.x < 128) lut[threadIdx.x] = (float)(2 * threadIdx.x) / 280.0f;
    __syncthreads();

    const int B   = blockIdx.x;
    const int xcd = B & 7;
    const int k   = B >> 3;
    const int b   = (k & 15) * 8 + xcd;        // [0,128), all slices same XCD
    const int s   = k >> 4;                    // slice 0..15
    const int q0  = s * 1024;

    const unsigned short* W0 = W16 + (size_t)b * HW2;
    const float4* packb = packed + (size_t)b * 16384;
    float4* out4 = (float4*)out;
    const size_t dkBase = (size_t)(b * 3) * QPB;
    const size_t O1 = (size_t)BS * 3 * QPB + (size_t)b * QPB;
    const size_t O2 = (size_t)BS * 4 * QPB + (size_t)b * QPB;

    #pragma unroll
    for (int t = 0; t < 4; ++t) {
        int qd = q0 + threadIdx.x + t * 256;   // quad of 4 cells
        uint2 a = ((const uint2*)W0)[qd];
        unsigned la[4] = { a.x & 0xFFFFu, a.x >> 16, a.y & 0xFFFFu, a.y >> 16 };
        float o0[4], o1[4], o2v[4], oc[4], om[4];
        #pragma unroll
        for (int j = 0; j < 4; ++j) {
            unsigned l = la[j];
            int ix = (int)(l & 255u) & ~1;     // even-snap (round-half-even)
            int iy = (int)(l >> 8) & ~1;
            float4 p = packb[(iy >> 1) * 128 + (ix >> 1)];
            float m = p.z;
            o0[j]  = lut[ix >> 1] * m;         // == (ix/280.0f)*m bit-exact
            o1[j]  = lut[iy >> 1] * m;
            o2v[j] = p.x;                      // depth*m (pre-masked)
            oc[j]  = p.y;
            om[j]  = m;
        }
        out4[dkBase + qd]           = make_float4(o0[0], o0[1], o0[2], o0[3]);
        out4[dkBase + QPB + qd]     = make_float4(o1[0], o1[1], o1[2], o1[3]);
        out4[dkBase + 2 * QPB + qd] = make_float4(o2v[0], o2v[1], o2v[2], o2v[3]);
        out4[O1 + qd]               = make_float4(oc[0], oc[1], oc[2], oc[3]);
        out4[O2 + qd]               = make_float4(om[0], om[1], om[2], om[3]);
    }
}

// ======================= FALLBACK (round-6 fused, measured) ================
#define QQ 4096
__global__ __launch_bounds__(NT, 8) void fused_kernel(
        const float* __restrict__ grid,
        const float* __restrict__ seg,
        const float* __restrict__ conf,
        const float* __restrict__ depth,
        float* __restrict__ out) {
    __shared__ unsigned int Wl[HW2 / 4];
    __shared__ unsigned long long segbits[4][256];
    __shared__ int red[16];
    __shared__ int flag_s;
    const int b       = blockIdx.x & (BS - 1);
    const int quarter = blockIdx.x >> 7;
    const int tid  = threadIdx.x;
    const int wave = tid >> 6;
    const int lane = tid & 63;
    const float* segb   = seg   + (size_t)b * HW2;
    const float* confb  = conf  + (size_t)b * HW2;
    const float* depthb = depth + (size_t)b * HW2;
    {
        uint4* Wz = (uint4*)Wl;
        #pragma unroll
        for (int k = 0; k < 4; ++k) Wz[tid + k * NT] = make_uint4(0u, 0u, 0u, 0u);
    }
    unsigned long long mbits = 0ULL;
    int cnt = 0;
    {
        const float4* s4 = (const float4*)segb;
        #pragma unroll
        for (int k = 0; k < 16; ++k) {
            int i = tid + k * NT;
            float4 v = s4[i];
            bool px = v.x > 0.5f, py = v.y > 0.5f, pz = v.z > 0.5f, pw = v.w > 0.5f;
            unsigned long long bx = __ballot(px), by = __ballot(py);
            unsigned long long bz = __ballot(pz), bw = __ballot(pw);
            if (lane == 0) {
                int wi = wave + k * 16;
                segbits[0][wi] = bx; segbits[1][wi] = by;
                segbits[2][wi] = bz; segbits[3][wi] = bw;
                cnt += __popcll(bx) + __popcll(by) + __popcll(bz) + __popcll(bw);
            }
            unsigned long long q = (px ? 1ULL : 0ULL) | (py ? 2ULL : 0ULL) |
                                   (pz ? 4ULL : 0ULL) | (pw ? 8ULL : 0ULL);
            mbits |= q << (k * 4);
        }
    }
    if (lane == 0) red[wave] = cnt;
    __syncthreads();
    if (tid == 0) {
        int t = 0;
        #pragma unroll
        for (int w = 0; w < 16; ++w) t += red[w];
        flag_s = (t == 0) ? 1 : 0;
    }
    __syncthreads();
    const int flagb = flag_s;
    {
        const float4* gx4 = (const float4*)(grid + (size_t)(2 * b) * HW2);
        const float4* gy4 = (const float4*)(grid + (size_t)(2 * b + 1) * HW2);
        int masked_max = -1;
        #pragma unroll 4
        for (int k = 0; k < 16; ++k) {
            int i = tid + k * NT;
            float4 X = gx4[i];
            float4 Y = gy4[i];
            int hw0 = i * 4;
            float xa[4] = {X.x, X.y, X.z, X.w};
            float ya[4] = {Y.x, Y.y, Y.z, Y.w};
            #pragma unroll
            for (int j = 0; j < 4; ++j) {
                bool m = flagb || ((mbits >> (k * 4 + j)) & 1ULL);
                if (m) {
                    float fx = (xa[j] + 1.0f) * 0.5f * 256.0f;
                    float fy = (ya[j] + 1.0f) * 0.5f * 256.0f;
                    int gxi = min(max((int)fx, 0), HW - 1);
                    int gyi = min(max((int)fy, 0), HW - 1);
                    if ((gyi >> 6) == quarter)
                        atomicMax(&Wl[(gyi & 63) * HW + gxi], (unsigned int)(hw0 + j));
                } else {
                    masked_max = hw0 + j;
                }
            }
        }
        int mm = masked_max;
        for (int off = 32; off > 0; off >>= 1) mm = max(mm, __shfl_xor(mm, off));
        if (quarter == 2 && lane == 0 && mm >= 0)
            atomicMax(&Wl[(128 & 63) * HW + 128], (unsigned int)mm);
    }
    __syncthreads();
    float4* out4 = (float4*)out;
    const size_t dkBase = (size_t)(b * 3) * QPB;
    const size_t O1q = (size_t)BS * 3 * QPB + (size_t)b * QPB;
    const size_t O2q = (size_t)BS * 4 * QPB + (size_t)b * QPB;
    #pragma unroll 4
    for (int k = 0; k < 4; ++k) {
        int i = tid + k * NT;
        uint4 wv = ((const uint4*)Wl)[i];
        unsigned la[4] = {wv.x, wv.y, wv.z, wv.w};
        float o0[4], o1[4], o2[4], oc[4], om[4];
        #pragma unroll
        for (int j = 0; j < 4; ++j) {
            unsigned l = la[j];
            int ix = (int)(l & 255u) & ~1;
            int iy = (int)(l >> 8) & ~1;
            int off = iy * HW + ix;
            int qq = off >> 2;
            float m;
            if (flagb) m = 1.0f;
            else       m = (float)((segbits[off & 3][qq >> 6] >> (qq & 63)) & 1ULL);
            o0[j] = ((float)ix / 280.0f) * m;
            o1[j] = ((float)iy / 280.0f) * m;
            o2[j] = depthb[off] * m;
            oc[j] = confb[off];
            om[j] = m;
        }
        size_t gq = (size_t)quarter * QQ + i;
        out4[dkBase + gq]           = make_float4(o0[0], o0[1], o0[2], o0[3]);
        out4[dkBase + QPB + gq]     = make_float4(o1[0], o1[1], o1[2], o1[3]);
        out4[dkBase + 2 * QPB + gq] = make_float4(o2[0], o2[1], o2[2], o2[3]);
        out4[O1q + gq]              = make_float4(oc[0], oc[1], oc[2], oc[3]);
        out4[O2q + gq]              = make_float4(om[0], om[1], om[2], om[3]);
    }
}

extern "C" void kernel_launch(void* const* d_in, const int* in_sizes, int n_in,
                              void* d_out, int out_size, void* d_ws, size_t ws_size,
                              hipStream_t stream) {
    const float* grid  = (const float*)d_in[0];
    const float* seg   = (const float*)d_in[1];
    const float* conf  = (const float*)d_in[2];
    const float* depth = (const float*)d_in[3];
    float* out = (float*)d_out;

    const size_t W16Bytes  = (size_t)BS * HW2 * sizeof(unsigned short);     // 16 MB
    const size_t packBytes = (size_t)BS * 16384 * sizeof(float4);           // 32 MB
    if (ws_size >= W16Bytes + packBytes) {
        unsigned short* W16 = (unsigned short*)d_ws;
        float4* packed = (float4*)((char*)d_ws + W16Bytes);
        scatter_kernel<<<BS * 4, NT, 0, stream>>>(grid, seg, conf, depth, W16, packed);
        gather_kernel<<<2048, 256, 0, stream>>>(W16, packed, out);
    } else {
        fused_kernel<<<BS * 4, NT, 0, stream>>>(grid, seg, conf, depth, out);
    }
}